// Round 11
// baseline (488.858 us; speedup 1.0000x reference)
//
#include <hip/hip_runtime.h>
#include <cstdint>
#include <cstddef>

// ---------------------------------------------------------------------------
// y = x @ W^T + lb  [B=32768, C=2048], K=2048 ; GroupNorm(32 groups of 64) ;
// per-row min ; out[0,c,b,0] = mins[b] + final_bias[c].
//
// R11: R10 skeleton frozen; MFMA shape swapped 16x16x32 -> 32x32x16
// (ubench 2382 vs 2075 TF, -17% MFMA pipe time, half the instructions).
// Wave 128x64 = 4 m-tiles x 2 n-tiles of 32x32, 4 k-steps of 16.
// Same staging/swizzle (r&7 == lane&7 holds; chunk = ks*2 + (lane>>5)).
// C/D layout (measured m74/m101): col=lane&31,
// row=(reg&3)+8*(reg>>2)+4*(lane>>5); epilogue reduces within each
// 32-lane half-wave (xor masks 1..16 stay inside the half).
// Converts merged into one launch.
// ---------------------------------------------------------------------------

#define AS1C(p) ((const __attribute__((address_space(1))) void*)(p))
#define AS3(p)  ((__attribute__((address_space(3))) void*)(p))
#define SB0()   __builtin_amdgcn_sched_barrier(0)

typedef short  short8  __attribute__((ext_vector_type(8)));
typedef int    int4v   __attribute__((ext_vector_type(4)));
typedef float  f32x16  __attribute__((ext_vector_type(16)));
typedef unsigned short ushort8 __attribute__((ext_vector_type(8)));

static constexpr int BDIM = 32768;
static constexpr int KDIM = 2048;
static constexpr int CDIM = 2048;
static constexpr int NT   = KDIM / 64;    // 32 K-tiles of BK=64

// ----------------------------- helpers -------------------------------------

__device__ __forceinline__ unsigned short f2bf(float f) {
    unsigned u = __float_as_uint(f);
    u += 0x7FFFu + ((u >> 16) & 1u);   // RNE
    return (unsigned short)(u >> 16);
}

__device__ __forceinline__ unsigned enc_min(float f) {
    unsigned u = __float_as_uint(f);
    return (u & 0x80000000u) ? ~u : (u | 0x80000000u);  // monotone float->uint
}

__device__ __forceinline__ float dec_min(unsigned e) {
    unsigned u = (e & 0x80000000u) ? (e ^ 0x80000000u) : ~e;
    return __uint_as_float(u);
}

// -------------------- k1: convert x and W in one launch ---------------------

__global__ void convert_kernel(const float* __restrict__ xs,
                               unsigned short* __restrict__ xd,
                               const float* __restrict__ ws,
                               unsigned short* __restrict__ wd,
                               int n8x, int n8tot) {
    int i = blockIdx.x * blockDim.x + threadIdx.x;
    if (i >= n8tot) return;
    const float4* s4;
    ushort8* d8;
    int j;
    if (i < n8x) { s4 = (const float4*)xs; d8 = (ushort8*)xd; j = i; }
    else         { s4 = (const float4*)ws; d8 = (ushort8*)wd; j = i - n8x; }
    float4 a = s4[2 * j];
    float4 b = s4[2 * j + 1];
    ushort8 o;
    o[0] = f2bf(a.x); o[1] = f2bf(a.y); o[2] = f2bf(a.z); o[3] = f2bf(a.w);
    o[4] = f2bf(b.x); o[5] = f2bf(b.y); o[6] = f2bf(b.z); o[7] = f2bf(b.w);
    d8[j] = o;
}

// ------------------- k2: fused GEMM + GroupNorm + row-min -------------------
// 256x256 tile, BK=64, 8 waves 2Mx4N (wave owns 128x64 = one GN group).

__global__ __launch_bounds__(512, 2) void gemm_gn_min(
    const unsigned short* __restrict__ Abf,   // x [32768,2048] bf16
    const unsigned short* __restrict__ Wbf,   // W [2048,2048]  bf16
    const float* __restrict__ lb,
    const float* __restrict__ gw,
    const float* __restrict__ gb,
    unsigned int* mins_enc)
{
    // A[d] at d*32768 (256 rows x 128B); B[d] at 65536 + d*32768
    __shared__ unsigned char lds[131072];

    const int tid  = threadIdx.x;
    const int wid  = tid >> 6;
    const int lane = tid & 63;

    // identity mapping: XCD = blk%8 = bj -> W-panel L2-resident per XCD.
    const int bj  = blockIdx.x & 7;           // C/256 = 8
    const int bi  = blockIdx.x >> 3;          // B/256 = 128
    const int row0 = bi * 256, col0 = bj * 256;
    const int wr = wid >> 2, wc = wid & 3;

    const int lr32 = lane & 31;   // fragment row/col within 32
    const int lq32 = lane >> 5;   // k-half selector (0/1)
    const int lx   = lane & 7;    // read-side XOR (== r&7 of every frag row)

    // ---- staging (proven scheme): linear LDS dest, inverse-swizzled global
    // source; physical chunk p of LDS row r holds logical p^(r&7).
    const int schunk = (lane & 7) ^ (lane >> 3);
    const unsigned short* aSrc =
        Abf + (size_t)(row0 + wid * 16 + (lane >> 3)) * KDIM + schunk * 8;
    const unsigned short* bSrc =
        Wbf + (size_t)(col0 + wid * 16 + (lane >> 3)) * KDIM + schunk * 8;

    auto stageA = [&](int d, int kt) {            // whole A tile: 4 gload_lds
#pragma unroll
        for (int h = 0; h < 2; ++h)
#pragma unroll
            for (int s = 0; s < 2; ++s)
                __builtin_amdgcn_global_load_lds(
                    AS1C(aSrc + (size_t)(h * 128 + s * 8) * KDIM + kt * 64),
                    AS3(&lds[d * 32768 + (h * 128 + wid * 16 + s * 8) * 128]),
                    16, 0, 0);
    };
    auto stageB = [&](int d, int kt) {            // whole B tile: 4 gload_lds
#pragma unroll
        for (int h = 0; h < 2; ++h)
#pragma unroll
            for (int s = 0; s < 2; ++s)
                __builtin_amdgcn_global_load_lds(
                    AS1C(bSrc + (size_t)(h * 128 + s * 8) * KDIM + kt * 64),
                    AS3(&lds[65536 + d * 32768 +
                             (h * 128 + wid * 16 + s * 8) * 128]), 16, 0, 0);
    };

    // read: row r, 16B-chunk ch (= ks*2 + lq32) -> physical chunk ch^(r&7)
    auto rdA = [&](int d, int r, int ch) -> int4v {
        return *(const int4v*)&lds[d * 32768 + r * 128 + ((ch) ^ lx) * 16];
    };
    auto rdB = [&](int d, int r, int ch) -> int4v {
        return *(const int4v*)&lds[65536 + d * 32768 + r * 128 +
                                   ((ch) ^ lx) * 16];
    };

    f32x16 acc[4][2] = {};
    int4v a01[2][4], a23[2][4], b0[4], b1[4];

    // ---- prologue: stage tile 0, drain, read tile-0 Q1 operands, issue A(1)
    stageA(0, 0); stageB(0, 0);
    asm volatile("s_waitcnt vmcnt(0)" ::: "memory");
    __builtin_amdgcn_s_barrier();
    asm volatile("" ::: "memory");
#pragma unroll
    for (int m = 0; m < 2; ++m)
#pragma unroll
        for (int ks = 0; ks < 4; ++ks)
            a01[m][ks] = rdA(0, wr * 128 + m * 32 + lr32, ks * 2 + lq32);
#pragma unroll
    for (int ks = 0; ks < 4; ++ks)
        b0[ks] = rdB(0, wc * 64 + lr32, ks * 2 + lq32);
    SB0();
    stageA(1, 1);                 // in-flight at tile-0 entry: A(1)
    SB0();

    for (int t = 0; t < NT; ++t) {
        const int c = t & 1, o = c ^ 1;
        const bool stB = (t + 1 < NT);
        const bool stA = (t + 2 < NT);

        // -------- entry: stage B(t+1) -> B[o]
        if (stB) stageB(o, t + 1);
        SB0();
        // -------- first-half reads: a23 (8) + b1 (4) from buf c
#pragma unroll
        for (int m = 0; m < 2; ++m)
#pragma unroll
            for (int ks = 0; ks < 4; ++ks)
                a23[m][ks] = rdA(c, wr * 128 + (m + 2) * 32 + lr32,
                                 ks * 2 + lq32);
#pragma unroll
        for (int ks = 0; ks < 4; ++ks)
            b1[ks] = rdB(c, wc * 64 + 32 + lr32, ks * 2 + lq32);
        SB0();
        // -------- Q1: m01 x n0 (prefetched -> ungated)
        __builtin_amdgcn_s_setprio(1);
#pragma unroll
        for (int m = 0; m < 2; ++m)
#pragma unroll
            for (int ks = 0; ks < 4; ++ks)
                acc[m][0] = __builtin_amdgcn_mfma_f32_32x32x16_bf16(
                    __builtin_bit_cast(short8, a01[m][ks]),
                    __builtin_bit_cast(short8, b0[ks]),
                    acc[m][0], 0, 0, 0);
        __builtin_amdgcn_s_setprio(0);
        SB0();
        // -------- Q2: m23 x n0 (compiler-counted lgkm on a23)
        __builtin_amdgcn_s_setprio(1);
#pragma unroll
        for (int m = 0; m < 2; ++m)
#pragma unroll
            for (int ks = 0; ks < 4; ++ks)
                acc[m + 2][0] = __builtin_amdgcn_mfma_f32_32x32x16_bf16(
                    __builtin_bit_cast(short8, a23[m][ks]),
                    __builtin_bit_cast(short8, b0[ks]),
                    acc[m + 2][0], 0, 0, 0);
        __builtin_amdgcn_s_setprio(0);
        SB0();
        // -------- mid: own reads drained; A(t+1),B(t+1) stages landed
        asm volatile("s_waitcnt lgkmcnt(0)" ::: "memory");
        asm volatile("s_waitcnt vmcnt(0)" ::: "memory");
        __builtin_amdgcn_s_barrier();
        asm volatile("" ::: "memory");
        // -------- stage A(t+2) -> A[c] (A[c] fully read by all waves)
        if (stA) stageA(c, t + 2);
        SB0();
        // -------- prefetch b0'(t+1) from B[o] (b0 free after Q2)
        if (stB) {
#pragma unroll
            for (int ks = 0; ks < 4; ++ks)
                b0[ks] = rdB(o, wc * 64 + lr32, ks * 2 + lq32);
        }
        SB0();
        // -------- Q3: m01 x n1 (b1 drained at mid -> register-only)
        __builtin_amdgcn_s_setprio(1);
#pragma unroll
        for (int m = 0; m < 2; ++m)
#pragma unroll
            for (int ks = 0; ks < 4; ++ks)
                acc[m][1] = __builtin_amdgcn_mfma_f32_32x32x16_bf16(
                    __builtin_bit_cast(short8, a01[m][ks]),
                    __builtin_bit_cast(short8, b1[ks]),
                    acc[m][1], 0, 0, 0);
        __builtin_amdgcn_s_setprio(0);
        SB0();
        // -------- prefetch a01'(t+1) from A[o] (a01 free after Q3)
        if (stB) {
#pragma unroll
            for (int m = 0; m < 2; ++m)
#pragma unroll
                for (int ks = 0; ks < 4; ++ks)
                    a01[m][ks] = rdA(o, wr * 128 + m * 32 + lr32,
                                     ks * 2 + lq32);
        }
        SB0();
        // -------- Q4: m23 x n1 (register-only; prefetches fly under)
        __builtin_amdgcn_s_setprio(1);
#pragma unroll
        for (int m = 0; m < 2; ++m)
#pragma unroll
            for (int ks = 0; ks < 4; ++ks)
                acc[m + 2][1] = __builtin_amdgcn_mfma_f32_32x32x16_bf16(
                    __builtin_bit_cast(short8, a23[m][ks]),
                    __builtin_bit_cast(short8, b1[ks]),
                    acc[m + 2][1], 0, 0, 0);
        __builtin_amdgcn_s_setprio(0);
        SB0();
        // -------- boundary: barrier WITHOUT waitcnt
        __builtin_amdgcn_s_barrier();
        asm volatile("" ::: "memory");
    }

    // ---- epilogue: +bias, groupnorm over this wave's 64-col group, row min.
    // C/D 32x32 layout: col = lane&31, row = (reg&3) + 8*(reg>>2) + 4*hi.
    float lbv[2], gwv[2], gbv[2];
    const int cbase = col0 + wc * 64 + lr32;
#pragma unroll
    for (int n = 0; n < 2; ++n) {
        int ch = cbase + n * 32;
        lbv[n] = lb[ch]; gwv[n] = gw[ch]; gbv[n] = gb[ch];
    }
    const int rbase = row0 + wr * 128 + 4 * lq32;

#pragma unroll
    for (int mt = 0; mt < 4; ++mt) {
#pragma unroll
        for (int reg = 0; reg < 16; ++reg) {
            float v0 = acc[mt][0][reg] + lbv[0];
            float v1 = acc[mt][1][reg] + lbv[1];
            float s1 = v0 + v1;
            float s2 = v0 * v0 + v1 * v1;
#pragma unroll
            for (int mask = 1; mask <= 16; mask <<= 1) {
                s1 += __shfl_xor(s1, mask, 64);   // stays within 32-lane half
                s2 += __shfl_xor(s2, mask, 64);
            }
            float mean = s1 * (1.f / 64.f);
            float var  = s2 * (1.f / 64.f) - mean * mean;
            float rstd = rsqrtf(var + 1e-5f);
            float mn = fminf((v0 - mean) * rstd * gwv[0] + gbv[0],
                             (v1 - mean) * rstd * gwv[1] + gbv[1]);
#pragma unroll
            for (int mask = 1; mask <= 16; mask <<= 1)
                mn = fminf(mn, __shfl_xor(mn, mask, 64));
            if (lr32 == 0) {
                int row = rbase + mt * 32 + (reg & 3) + 8 * (reg >> 2);
                atomicMin(mins_enc + row, enc_min(mn));
            }
        }
    }
}

// --------------------------- k3: broadcast ----------------------------------

__global__ void finalize_kernel(const unsigned int* mins_enc,
                                const float* __restrict__ fb, float* out) {
    size_t t = (size_t)blockIdx.x * 256 + threadIdx.x;
    size_t flat = t * 4;                      // 4 consecutive b, same c
    int c = (int)(flat >> 15);
    if (c == 1088) return;                    // mins live here; fixup later
    int b = (int)(flat & 32767);
    uint4 e = *(const uint4*)(mins_enc + b);
    float bias = fb[c];
    float4 o;
    o.x = dec_min(e.x) + bias;
    o.y = dec_min(e.y) + bias;
    o.z = dec_min(e.z) + bias;
    o.w = dec_min(e.w) + bias;
    *(float4*)(out + flat) = o;
}

__global__ void fixup_kernel(const float* __restrict__ fb, float* out) {
    int b = blockIdx.x * 256 + threadIdx.x;
    size_t idx = (size_t)1088 * 32768 + b;
    unsigned e = ((const unsigned*)out)[idx];  // read own cell first
    out[idx] = dec_min(e) + fb[1088];
}

// ----------------------------- launcher -------------------------------------

extern "C" void kernel_launch(void* const* d_in, const int* in_sizes, int n_in,
                              void* d_out, int out_size, void* d_ws, size_t ws_size,
                              hipStream_t stream) {
    const float* x  = (const float*)d_in[0];
    const float* w  = (const float*)d_in[1];
    const float* lb = (const float*)d_in[2];
    const float* gw = (const float*)d_in[3];
    const float* gb = (const float*)d_in[4];
    const float* fb = (const float*)d_in[5];
    float* out = (float*)d_out;

    // scratch regions inside d_out (268 MB total):
    unsigned short* xb = (unsigned short*)d_out;                        // 128 MiB
    unsigned short* wb = (unsigned short*)((char*)d_out + 134217728);   //   8 MiB
    unsigned int* mins = (unsigned int*)((char*)d_out + (size_t)1088 * 32768 * 4);

    // k1: fp32 -> bf16 (x and W in one launch)
    {
        int n8x = (BDIM * KDIM) / 8;          // 8388608
        int n8t = n8x + (CDIM * KDIM) / 8;    // + 524288
        convert_kernel<<<(n8t + 255) / 256, 256, 0, stream>>>(
            x, xb, w, wb, n8x, n8t);
    }

    // init encoded mins to 0xFFFFFFFF (>= every encoding)
    hipMemsetAsync((void*)mins, 0xFF, (size_t)BDIM * 4, stream);

    // k2: fused GEMM + GN + min  (256x256 tiles -> 128x8 = 1024 blocks)
    gemm_gn_min<<<dim3((BDIM / 256) * (CDIM / 256)), dim3(512), 0, stream>>>(
        xb, wb, lb, gw, gb, mins);

    // k3: broadcast (skips c==1088), then fixup c==1088
    finalize_kernel<<<(BDIM / 4) * CDIM / 256, 256, 0, stream>>>(mins, fb, out);
    fixup_kernel<<<BDIM / 256, 256, 0, stream>>>(fb, out);
}